// Round 2
// baseline (2208.561 us; speedup 1.0000x reference)
//
#include <hip/hip_runtime.h>
#include <hip/hip_bf16.h>

#define Bn 64
#define Sn 256
#define In 128
#define Hn 128
#define NUNF 6
#define EPSC 1e-8f
#define L2E 1.4426950408889634f
#define TT 16
#define QG 8          // j-groups (threads = QG*Hn = 1024)
#define JPT 16        // j's per thread

// ---------------- workspace layout (floats) ----------------
enum {
  OFF_A2   = 0,                    // -sigma*log2e          (H*H)
  OFF_B2   = OFF_A2   + Hn*Hn,     //  sigma*mu*log2e       (H*H)
  OFF_W    = OFF_B2   + Hn*Hn,     //  softplus(w)          (H*H)
  OFF_WE   = OFF_W    + Hn*Hn,     //  softplus(w)*erev     (H*H)
  OFF_SA2  = OFF_WE   + Hn*Hn,     //  sensory equivalents  (I*H)
  OFF_SB2  = OFF_SA2  + In*Hn,
  OFF_SW   = OFF_SB2  + In*Hn,
  OFF_SWE  = OFF_SW   + In*Hn,
  OFF_PHT  = OFF_SWE  + In*Hn,     //  phase_W^T [j][h]     (H*H)
  OFF_SAT  = OFF_PHT  + Hn*Hn,     //  sa_W^T [j][h]        (H*H)
  OFF_CMT  = OFF_SAT  + Hn*Hn,     //  softplus(cm)*UNFOLDS (H)
  OFF_GL   = OFF_CMT  + Hn,        //  softplus(gleak)      (H)
  OFF_GLV  = OFF_GL   + Hn,        //  gl*vleak             (H)
  OFF_AAMP = OFF_GLV  + Hn,        //  alpha*amplitude      (H)
  OFF_NUMS = OFF_AAMP + Hn,        //  sensory num (B,S,H)
  OFF_DENS = OFF_NUMS + Bn*Sn*Hn,  //  sensory den (B,S,H)
  WS_FLOATS = OFF_DENS + Bn*Sn*Hn
};

// ---------------- fast math wrappers ----------------
__device__ __forceinline__ float fexp2(float x) {
#if __has_builtin(__builtin_amdgcn_exp2f)
  return __builtin_amdgcn_exp2f(x);
#else
  return exp2f(x);
#endif
}
__device__ __forceinline__ float frcp(float x) {
#if __has_builtin(__builtin_amdgcn_rcpf)
  return __builtin_amdgcn_rcpf(x);
#else
  return 1.0f / x;
#endif
}
__device__ __forceinline__ float fsigmoid(float x) {
  return frcp(1.0f + fexp2(-x * L2E));
}
__device__ __forceinline__ float fast_sin(float ang) {
#if __has_builtin(__builtin_amdgcn_sinf)
  float r = ang * 0.15915494309189535f;  // revolutions
  r = r - rintf(r);
  return __builtin_amdgcn_sinf(r);
#else
  return sinf(ang);
#endif
}

// ---------------- kernel 1: parameter transforms ----------------
__global__ void k_prep(const float* __restrict__ sigma, const float* __restrict__ mu,
                       const float* __restrict__ w, const float* __restrict__ erev,
                       const float* __restrict__ s_sigma, const float* __restrict__ s_mu,
                       const float* __restrict__ s_w, const float* __restrict__ s_erev,
                       const float* __restrict__ gleak, const float* __restrict__ vleak,
                       const float* __restrict__ cm, const float* __restrict__ amplitude,
                       const float* __restrict__ alpha_p,
                       const float* __restrict__ phase_W, const float* __restrict__ sa_W,
                       float* __restrict__ ws)
{
  int i = blockIdx.x * blockDim.x + threadIdx.x;
  if (i >= Hn * Hn) return;
  {
    float sg = sigma[i];
    ws[OFF_A2 + i] = -sg * L2E;
    ws[OFF_B2 + i] = sg * mu[i] * L2E;
    float Wv = log1pf(expf(w[i]));          // softplus
    ws[OFF_W  + i] = Wv;
    ws[OFF_WE + i] = Wv * erev[i];
  }
  {
    float ss = s_sigma[i];
    ws[OFF_SA2 + i] = -ss * L2E;
    ws[OFF_SB2 + i] = ss * s_mu[i] * L2E;
    float SWv = log1pf(expf(s_w[i]));
    ws[OFF_SW  + i] = SWv;
    ws[OFF_SWE + i] = SWv * s_erev[i];
  }
  {
    int j = i >> 7, h = i & (Hn - 1);
    ws[OFF_PHT + i] = phase_W[h * Hn + j];  // transpose to [j][h]
    ws[OFF_SAT + i] = sa_W[h * Hn + j];
  }
  if (i < Hn) {
    float gl = log1pf(expf(gleak[i]));
    ws[OFF_CMT  + i] = log1pf(expf(cm[i])) * (float)NUNF;  // DT == 1
    ws[OFF_GL   + i] = gl;
    ws[OFF_GLV  + i] = gl * vleak[i];
    ws[OFF_AAMP + i] = alpha_p[0] * amplitude[i];
  }
}

// ---------------- kernel 2: sensory synapse sums (fully parallel) ----------------
__global__ __launch_bounds__(128, 4) void k_sensory(
    const float* __restrict__ x, const float* __restrict__ input_w,
    const float* __restrict__ input_b, const float* __restrict__ ws,
    float* __restrict__ onum, float* __restrict__ oden)
{
  __shared__ float xs[TT * In];
  int b = blockIdx.x, tc = blockIdx.y;
  int t0 = tc * TT;
  int h = threadIdx.x;

  for (int k = h; k < TT * In; k += 128) {
    int tt = k >> 7, i = k & (In - 1);
    xs[k] = x[((size_t)b * Sn + t0 + tt) * In + i] * input_w[i] + input_b[i];
  }
  __syncthreads();

  const float* sa2 = ws + OFF_SA2;
  const float* sb2 = ws + OFF_SB2;
  const float* SW  = ws + OFF_SW;
  const float* SWE = ws + OFF_SWE;

  float num[TT], den[TT];
#pragma unroll
  for (int tt = 0; tt < TT; tt++) { num[tt] = 0.f; den[tt] = 0.f; }

  for (int i = 0; i < In; i++) {
    float A  = sa2[i * Hn + h];
    float Bc = sb2[i * Hn + h];
    float Wv = SW [i * Hn + h];
    float Ev = SWE[i * Hn + h];
#pragma unroll
    for (int tt = 0; tt < TT; tt++) {
      float e = fexp2(fmaf(A, xs[tt * In + i], Bc));
      float r = frcp(1.0f + e);
      den[tt] = fmaf(Wv, r, den[tt]);
      num[tt] = fmaf(Ev, r, num[tt]);
    }
  }
#pragma unroll
  for (int tt = 0; tt < TT; tt++) {
    size_t o = ((size_t)b * Sn + t0 + tt) * Hn + h;
    onum[o] = num[tt];
    oden[o] = den[tt];
  }
}

// ---------------- kernel 3: recurrent scan (1 block == 1 batch chain) ----------------
// 1024 threads = 16 waves (4/SIMD). Thread (q,h): q = tid>>7 owns j in
// [q*16, q*16+16), h = tid&127 is the output column. 3 param arrays in
// registers (48 VGPR): a2 = -sigma*log2e, b2 = sigma*mu*log2e,
// sWE = softplus(w)*erev. den uses fabs(sWE) == softplus(w) as a free
// input modifier (erev is exactly +-1).
__global__ __launch_bounds__(QG * Hn, 4) void k_recurrent(
    const float* __restrict__ ws, const float* __restrict__ h0,
    const float* __restrict__ omega, const float* __restrict__ phase_b,
    const float* __restrict__ beta_p, float* __restrict__ out)
{
  __shared__ float phT_s[Hn * Hn];       // 64 KB
  __shared__ float saT_s[Hn * Hn];       // 64 KB
  __shared__ __align__(16) float vbuf[Hn];
  __shared__ float sgbuf[Hn];
  __shared__ float pnum[QG][Hn];
  __shared__ float pden[QG][Hn];

  int b = blockIdx.x;
  int tid = threadIdx.x;
  int h = tid & (Hn - 1);
  int q = tid >> 7;            // 0..7, wave-uniform
  int j0 = q * JPT;

  // per-thread recurrent synapse params in registers (16 j x 3 = 48 VGPR)
  float a2[JPT], b2[JPT], sWE[JPT];
#pragma unroll
  for (int k = 0; k < JPT; k++) {
    int idx = (j0 + k) * Hn + h;
    a2[k]  = ws[OFF_A2 + idx];
    b2[k]  = ws[OFF_B2 + idx];
    sWE[k] = ws[OFF_WE + idx];
  }
  for (int k = tid; k < Hn * Hn; k += QG * Hn) {
    phT_s[k] = ws[OFF_PHT + k];
    saT_s[k] = ws[OFF_SAT + k];
  }

  float cmt  = ws[OFF_CMT  + h];
  float gl   = ws[OFF_GL   + h];
  float glv  = ws[OFF_GLV  + h];
  float aamp = ws[OFF_AAMP + h];
  float om   = omega[h];
  float phb  = phase_b[h];
  float beta = beta_p[0];
  float den_base = cmt + gl + EPSC;

  const float* nums = ws + OFF_NUMS + (size_t)b * Sn * Hn;
  const float* dens = ws + OFF_DENS + (size_t)b * Sn * Hn;
  float* outb = out + (size_t)b * Sn * Hn;

  if (tid < Hn) vbuf[tid] = h0[b * Hn + tid];
  __syncthreads();

  for (int t = 0; t < Sn; t++) {
    // prefetch sensory sums for this step; used ~1 unfold later
    float sn = 0.f, sd = 0.f;
    if (tid < Hn) { sn = nums[t * Hn + tid]; sd = dens[t * Hn + tid]; }

    // ---- 6 semi-implicit ODE unfolds ----
    for (int u = 0; u < NUNF; u++) {
      float num = 0.f, den = 0.f;
#pragma unroll
      for (int k4 = 0; k4 < JPT; k4 += 4) {
        float4 vv = *(const float4*)(vbuf + j0 + k4);
        float vj[4] = {vv.x, vv.y, vv.z, vv.w};
#pragma unroll
        for (int m = 0; m < 4; m++) {
          int k = k4 + m;
          float e = fexp2(fmaf(a2[k], vj[m], b2[k]));
          float r = frcp(1.0f + e);
          den = fmaf(fabsf(sWE[k]), r, den);   // |W*erev| = W, free modifier
          num = fmaf(sWE[k],        r, num);
        }
      }
      pnum[q][h] = num;
      pden[q][h] = den;
      __syncthreads();
      if (tid < Hn) {
        float wn = sn, wd = sd;
#pragma unroll
        for (int s = 0; s < QG; s++) { wn += pnum[s][tid]; wd += pden[s][tid]; }
        float v = vbuf[tid];
        vbuf[tid] = fmaf(cmt, v, glv + wn) * frcp(den_base + wd);
      }
      __syncthreads();
    }

    // ---- oscillatory pulse: phi = v @ phase_W^T + phase_b ----
    {
      float acc = 0.f;
#pragma unroll
      for (int k = 0; k < JPT; k++)
        acc = fmaf(phT_s[(j0 + k) * Hn + h], vbuf[j0 + k], acc);
      pnum[q][h] = acc;
    }
    __syncthreads();
    if (tid < Hn) {
      float phi = phb;
#pragma unroll
      for (int s = 0; s < QG; s++) phi += pnum[s][tid];
      float v = vbuf[tid];
      v += aamp * fast_sin(om * (float)t + phi);
      sgbuf[tid] = fsigmoid(v);
      vbuf[tid] = v;
    }
    __syncthreads();

    // ---- self-attend: v += beta * (sigmoid(v) @ sa_W^T) ----
    {
      float acc = 0.f;
#pragma unroll
      for (int k = 0; k < JPT; k++)
        acc = fmaf(saT_s[(j0 + k) * Hn + h], sgbuf[j0 + k], acc);
      pnum[q][h] = acc;
    }
    __syncthreads();
    if (tid < Hn) {
      float acc = 0.f;
#pragma unroll
      for (int s = 0; s < QG; s++) acc += pnum[s][tid];
      float v = fmaf(beta, acc, vbuf[tid]);
      vbuf[tid] = v;
      outb[t * Hn + tid] = v;
    }
    __syncthreads();
  }

  if (tid < Hn) out[(size_t)Bn * Sn * Hn + b * Hn + tid] = vbuf[tid];
}

// ---------------- launcher ----------------
extern "C" void kernel_launch(void* const* d_in, const int* in_sizes, int n_in,
                              void* d_out, int out_size, void* d_ws, size_t ws_size,
                              hipStream_t stream) {
  const float* x         = (const float*)d_in[0];
  const float* h0        = (const float*)d_in[1];
  const float* input_w   = (const float*)d_in[2];
  const float* input_b   = (const float*)d_in[3];
  const float* gleak     = (const float*)d_in[4];
  const float* vleak     = (const float*)d_in[5];
  const float* cm        = (const float*)d_in[6];
  const float* sigma     = (const float*)d_in[7];
  const float* mu        = (const float*)d_in[8];
  const float* w         = (const float*)d_in[9];
  const float* erev      = (const float*)d_in[10];
  const float* s_sigma   = (const float*)d_in[11];
  const float* s_mu      = (const float*)d_in[12];
  const float* s_w       = (const float*)d_in[13];
  const float* s_erev    = (const float*)d_in[14];
  const float* amplitude = (const float*)d_in[15];
  const float* omega     = (const float*)d_in[16];
  const float* phase_W   = (const float*)d_in[17];
  const float* phase_b   = (const float*)d_in[18];
  const float* alpha     = (const float*)d_in[19];
  const float* sa_W      = (const float*)d_in[20];
  const float* beta      = (const float*)d_in[21];

  float* ws  = (float*)d_ws;
  float* out = (float*)d_out;

  hipLaunchKernelGGL(k_prep, dim3(64), dim3(256), 0, stream,
                     sigma, mu, w, erev, s_sigma, s_mu, s_w, s_erev,
                     gleak, vleak, cm, amplitude, alpha, phase_W, sa_W, ws);
  hipLaunchKernelGGL(k_sensory, dim3(Bn, Sn / TT), dim3(128), 0, stream,
                     x, input_w, input_b, ws, ws + OFF_NUMS, ws + OFF_DENS);
  hipLaunchKernelGGL(k_recurrent, dim3(Bn), dim3(QG * Hn), 0, stream,
                     ws, h0, omega, phase_b, beta, out);
}

// Round 3
// 2047.868 us; speedup vs baseline: 1.0785x; 1.0785x over previous
//
#include <hip/hip_runtime.h>
#include <hip/hip_bf16.h>

#define Bn 64
#define Sn 256
#define In 128
#define Hn 128
#define NUNF 6
#define EPSC 1e-8f
#define L2E 1.4426950408889634f
#define TT 16
#define QG 8          // j-groups per h (threads = QG*Hn = 1024)
#define JPT 16        // j's per thread

// ---------------- workspace layout (floats) ----------------
enum {
  OFF_A2   = 0,                    // -sigma*log2e          (H*H)
  OFF_B2   = OFF_A2   + Hn*Hn,     //  sigma*mu*log2e       (H*H)
  OFF_W    = OFF_B2   + Hn*Hn,     //  softplus(w)          (H*H)
  OFF_WE   = OFF_W    + Hn*Hn,     //  softplus(w)*erev     (H*H)
  OFF_SA2  = OFF_WE   + Hn*Hn,     //  sensory equivalents  (I*H)
  OFF_SB2  = OFF_SA2  + In*Hn,
  OFF_SW   = OFF_SB2  + In*Hn,
  OFF_SWE  = OFF_SW   + In*Hn,
  OFF_PHT  = OFF_SWE  + In*Hn,     //  phase_W^T [j][h]     (H*H)
  OFF_SAT  = OFF_PHT  + Hn*Hn,     //  sa_W^T [j][h]        (H*H)
  OFF_CMT  = OFF_SAT  + Hn*Hn,     //  softplus(cm)*UNFOLDS (H)
  OFF_GL   = OFF_CMT  + Hn,        //  softplus(gleak)      (H)
  OFF_GLV  = OFF_GL   + Hn,        //  gl*vleak             (H)
  OFF_AAMP = OFF_GLV  + Hn,        //  alpha*amplitude      (H)
  OFF_NUMS = OFF_AAMP + Hn,        //  sensory num (B,S,H)
  OFF_DENS = OFF_NUMS + Bn*Sn*Hn,  //  sensory den (B,S,H)
  WS_FLOATS = OFF_DENS + Bn*Sn*Hn
};

// ---------------- fast math wrappers ----------------
__device__ __forceinline__ float fexp2(float x) {
#if __has_builtin(__builtin_amdgcn_exp2f)
  return __builtin_amdgcn_exp2f(x);
#else
  return exp2f(x);
#endif
}
__device__ __forceinline__ float frcp(float x) {
#if __has_builtin(__builtin_amdgcn_rcpf)
  return __builtin_amdgcn_rcpf(x);
#else
  return 1.0f / x;
#endif
}
__device__ __forceinline__ float fsigmoid(float x) {
  return frcp(1.0f + fexp2(-x * L2E));
}
__device__ __forceinline__ float fast_sin(float ang) {
#if __has_builtin(__builtin_amdgcn_sinf)
  float r = ang * 0.15915494309189535f;  // revolutions
  r = r - rintf(r);
  return __builtin_amdgcn_sinf(r);
#else
  return sinf(ang);
#endif
}

// 8-lane mirror-butterfly allreduce over lanes (tid&7) within aligned groups.
// Steps: row_half_mirror (i<->7-i in 8), quad mirror (i<->3-i in 4), xor1.
template <int CTRL>
__device__ __forceinline__ float dpp_add(float x) {
  int t = __builtin_amdgcn_update_dpp(0, __float_as_int(x), CTRL, 0xf, 0xf, true);
  return x + __int_as_float(t);
}
__device__ __forceinline__ float reduce8(float x) {
  x = dpp_add<0x141>(x);  // row_half_mirror
  x = dpp_add<0x1B>(x);   // quad_perm [3,2,1,0]
  x = dpp_add<0xB1>(x);   // quad_perm [1,0,3,2]
  return x;
}

// swizzled LDS index for [j][h] matrices: avoids 8-way bank conflicts for
// the (h = tid>>3, c = tid&7) lane layout. j>>4 == c for a thread's own j's.
__device__ __forceinline__ int swz(int j, int h) {
  return j * Hn + ((h + 4 * (j >> 4)) & (Hn - 1));
}

// ---------------- kernel 1: parameter transforms ----------------
__global__ void k_prep(const float* __restrict__ sigma, const float* __restrict__ mu,
                       const float* __restrict__ w, const float* __restrict__ erev,
                       const float* __restrict__ s_sigma, const float* __restrict__ s_mu,
                       const float* __restrict__ s_w, const float* __restrict__ s_erev,
                       const float* __restrict__ gleak, const float* __restrict__ vleak,
                       const float* __restrict__ cm, const float* __restrict__ amplitude,
                       const float* __restrict__ alpha_p,
                       const float* __restrict__ phase_W, const float* __restrict__ sa_W,
                       float* __restrict__ ws)
{
  int i = blockIdx.x * blockDim.x + threadIdx.x;
  if (i >= Hn * Hn) return;
  {
    float sg = sigma[i];
    ws[OFF_A2 + i] = -sg * L2E;
    ws[OFF_B2 + i] = sg * mu[i] * L2E;
    float Wv = log1pf(expf(w[i]));          // softplus
    ws[OFF_W  + i] = Wv;
    ws[OFF_WE + i] = Wv * erev[i];
  }
  {
    float ss = s_sigma[i];
    ws[OFF_SA2 + i] = -ss * L2E;
    ws[OFF_SB2 + i] = ss * s_mu[i] * L2E;
    float SWv = log1pf(expf(s_w[i]));
    ws[OFF_SW  + i] = SWv;
    ws[OFF_SWE + i] = SWv * s_erev[i];
  }
  {
    int j = i >> 7, h = i & (Hn - 1);
    ws[OFF_PHT + i] = phase_W[h * Hn + j];  // transpose to [j][h]
    ws[OFF_SAT + i] = sa_W[h * Hn + j];
  }
  if (i < Hn) {
    float gl = log1pf(expf(gleak[i]));
    ws[OFF_CMT  + i] = log1pf(expf(cm[i])) * (float)NUNF;  // DT == 1
    ws[OFF_GL   + i] = gl;
    ws[OFF_GLV  + i] = gl * vleak[i];
    ws[OFF_AAMP + i] = alpha_p[0] * amplitude[i];
  }
}

// ---------------- kernel 2: sensory synapse sums (fully parallel) ----------------
__global__ __launch_bounds__(128, 4) void k_sensory(
    const float* __restrict__ x, const float* __restrict__ input_w,
    const float* __restrict__ input_b, const float* __restrict__ ws,
    float* __restrict__ onum, float* __restrict__ oden)
{
  __shared__ float xs[TT * In];
  int b = blockIdx.x, tc = blockIdx.y;
  int t0 = tc * TT;
  int h = threadIdx.x;

  for (int k = h; k < TT * In; k += 128) {
    int tt = k >> 7, i = k & (In - 1);
    xs[k] = x[((size_t)b * Sn + t0 + tt) * In + i] * input_w[i] + input_b[i];
  }
  __syncthreads();

  const float* sa2 = ws + OFF_SA2;
  const float* sb2 = ws + OFF_SB2;
  const float* SW  = ws + OFF_SW;
  const float* SWE = ws + OFF_SWE;

  float num[TT], den[TT];
#pragma unroll
  for (int tt = 0; tt < TT; tt++) { num[tt] = 0.f; den[tt] = 0.f; }

  for (int i = 0; i < In; i++) {
    float A  = sa2[i * Hn + h];
    float Bc = sb2[i * Hn + h];
    float Wv = SW [i * Hn + h];
    float Ev = SWE[i * Hn + h];
#pragma unroll
    for (int tt = 0; tt < TT; tt++) {
      float e = fexp2(fmaf(A, xs[tt * In + i], Bc));
      float r = frcp(1.0f + e);
      den[tt] = fmaf(Wv, r, den[tt]);
      num[tt] = fmaf(Ev, r, num[tt]);
    }
  }
#pragma unroll
  for (int tt = 0; tt < TT; tt++) {
    size_t o = ((size_t)b * Sn + t0 + tt) * Hn + h;
    onum[o] = num[tt];
    oden[o] = den[tt];
  }
}

// ---------------- kernel 3: recurrent scan (1 block == 1 batch chain) ----------------
// 1024 threads, layout: h = tid>>3 (output neuron), c = tid&7 (j-group),
// j range [16c, 16c+16). Partial sums for one h sit in 8 adjacent lanes ->
// DPP mirror-butterfly allreduce, v-update computed redundantly per lane
// (own-h v carried in register vcur). vbuf double-buffered -> 1 barrier per
// unfold, 8 barriers per step total.
__global__ __launch_bounds__(QG * Hn, 4)
__attribute__((amdgpu_waves_per_eu(4, 4)))
void k_recurrent(
    const float* __restrict__ ws, const float* __restrict__ h0,
    const float* __restrict__ omega, const float* __restrict__ phase_b,
    const float* __restrict__ beta_p, float* __restrict__ out)
{
  __shared__ float phT_s[Hn * Hn];            // 64 KB, swizzled [j][h]
  __shared__ float saT_s[Hn * Hn];            // 64 KB, swizzled [j][h]
  __shared__ __align__(16) float vb[2][Hn];   // double-buffered state
  __shared__ __align__(16) float sgbuf[Hn];

  int b = blockIdx.x;
  int tid = threadIdx.x;
  int h = tid >> 3;            // 0..127
  int c = tid & 7;             // 0..7
  int j0 = c * JPT;

  // rotated param load: register slot s=4m+e holds j = j0 + 4*((m+c)&3) + e,
  // matching the rotated float4 vbuf reads (kills 4-way LDS conflicts).
  float a2[JPT], b2[JPT], sWE[JPT];
#pragma unroll
  for (int m = 0; m < 4; m++) {
    int mm = (m + c) & 3;
#pragma unroll
    for (int e = 0; e < 4; e++) {
      int s = 4 * m + e;
      int idx = (j0 + 4 * mm + e) * Hn + h;
      a2[s]  = ws[OFF_A2 + idx];
      b2[s]  = ws[OFF_B2 + idx];
      sWE[s] = ws[OFF_WE + idx];
    }
  }
  for (int k = tid; k < Hn * Hn; k += QG * Hn) {
    int j = k >> 7, hh = k & (Hn - 1);
    phT_s[swz(j, hh)] = ws[OFF_PHT + k];
    saT_s[swz(j, hh)] = ws[OFF_SAT + k];
  }

  float cmt  = ws[OFF_CMT  + h];
  float gl   = ws[OFF_GL   + h];
  float glv  = ws[OFF_GLV  + h];
  float aamp = ws[OFF_AAMP + h];
  float om   = omega[h];
  float phb  = phase_b[h];
  float beta = beta_p[0];
  float den_base = cmt + gl + EPSC;
  int hs = (h + 4 * c) & (Hn - 1);   // per-thread swizzled column

  const float* nums = ws + OFF_NUMS + (size_t)b * Sn * Hn;
  const float* dens = ws + OFF_DENS + (size_t)b * Sn * Hn;
  float* outb = out + (size_t)b * Sn * Hn;

  float vcur = h0[b * Hn + h];
  if (c == 0) vb[0][h] = vcur;
  __syncthreads();

  for (int t = 0; t < Sn; t++) {
    float sn = nums[t * Hn + h];   // 8 lanes same addr -> broadcast
    float sd = dens[t * Hn + h];

    // ---- 6 semi-implicit ODE unfolds, ping-pong vb[u&1] -> vb[(u&1)^1] ----
#pragma unroll
    for (int u = 0; u < NUNF; u++) {
      int p = u & 1;
      const float4* vbp4 = (const float4*)(&vb[p][0]);
      float num = 0.f, den = 0.f;
#pragma unroll
      for (int m = 0; m < 4; m++) {
        int mm = (m + c) & 3;
        float4 v4 = vbp4[4 * c + mm];
        float vj[4] = {v4.x, v4.y, v4.z, v4.w};
#pragma unroll
        for (int e = 0; e < 4; e++) {
          int s = 4 * m + e;
          float ex = fexp2(fmaf(a2[s], vj[e], b2[s]));
          float r = frcp(1.0f + ex);
          den = fmaf(fabsf(sWE[s]), r, den);   // |W*erev| = W (erev = +-1)
          num = fmaf(sWE[s],        r, num);
        }
      }
      num = reduce8(num);
      den = reduce8(den);
      float vnew = fmaf(cmt, vcur, glv + sn + num) * frcp(den_base + sd + den);
      if (c == 0) vb[p ^ 1][h] = vnew;
      vcur = vnew;
      __syncthreads();
    }

    // ---- oscillatory pulse: phi = v @ phase_W^T + phase_b ----
    {
      const float4* vb04 = (const float4*)(&vb[0][0]);
      float acc = 0.f;
#pragma unroll
      for (int m = 0; m < 4; m++) {
        int mm = (m + c) & 3;
        float4 v4 = vb04[4 * c + mm];
        float vj[4] = {v4.x, v4.y, v4.z, v4.w};
#pragma unroll
        for (int e = 0; e < 4; e++) {
          int j = j0 + 4 * mm + e;
          acc = fmaf(phT_s[j * Hn + hs], vj[e], acc);
        }
      }
      acc = reduce8(acc);
      float phi = phb + acc;
      float v = vcur + aamp * fast_sin(om * (float)t + phi);
      if (c == 0) sgbuf[h] = fsigmoid(v);
      vcur = v;
    }
    __syncthreads();

    // ---- self-attend: v += beta * (sigmoid(v) @ sa_W^T) ----
    {
      const float4* sg4 = (const float4*)(&sgbuf[0]);
      float acc = 0.f;
#pragma unroll
      for (int m = 0; m < 4; m++) {
        int mm = (m + c) & 3;
        float4 s4 = sg4[4 * c + mm];
        float sj[4] = {s4.x, s4.y, s4.z, s4.w};
#pragma unroll
        for (int e = 0; e < 4; e++) {
          int j = j0 + 4 * mm + e;
          acc = fmaf(saT_s[j * Hn + hs], sj[e], acc);
        }
      }
      acc = reduce8(acc);
      float v = fmaf(beta, acc, vcur);
      vcur = v;
      if (c == 0) {
        vb[0][h] = v;                 // next step's unfold 0 reads vb[0]
        outb[t * Hn + h] = v;
      }
    }
    __syncthreads();
  }

  if (c == 0) out[(size_t)Bn * Sn * Hn + b * Hn + h] = vcur;
}

// ---------------- launcher ----------------
extern "C" void kernel_launch(void* const* d_in, const int* in_sizes, int n_in,
                              void* d_out, int out_size, void* d_ws, size_t ws_size,
                              hipStream_t stream) {
  const float* x         = (const float*)d_in[0];
  const float* h0        = (const float*)d_in[1];
  const float* input_w   = (const float*)d_in[2];
  const float* input_b   = (const float*)d_in[3];
  const float* gleak     = (const float*)d_in[4];
  const float* vleak     = (const float*)d_in[5];
  const float* cm        = (const float*)d_in[6];
  const float* sigma     = (const float*)d_in[7];
  const float* mu        = (const float*)d_in[8];
  const float* w         = (const float*)d_in[9];
  const float* erev      = (const float*)d_in[10];
  const float* s_sigma   = (const float*)d_in[11];
  const float* s_mu      = (const float*)d_in[12];
  const float* s_w       = (const float*)d_in[13];
  const float* s_erev    = (const float*)d_in[14];
  const float* amplitude = (const float*)d_in[15];
  const float* omega     = (const float*)d_in[16];
  const float* phase_W   = (const float*)d_in[17];
  const float* phase_b   = (const float*)d_in[18];
  const float* alpha     = (const float*)d_in[19];
  const float* sa_W      = (const float*)d_in[20];
  const float* beta      = (const float*)d_in[21];

  float* ws  = (float*)d_ws;
  float* out = (float*)d_out;

  hipLaunchKernelGGL(k_prep, dim3(64), dim3(256), 0, stream,
                     sigma, mu, w, erev, s_sigma, s_mu, s_w, s_erev,
                     gleak, vleak, cm, amplitude, alpha, phase_W, sa_W, ws);
  hipLaunchKernelGGL(k_sensory, dim3(Bn, Sn / TT), dim3(128), 0, stream,
                     x, input_w, input_b, ws, ws + OFF_NUMS, ws + OFF_DENS);
  hipLaunchKernelGGL(k_recurrent, dim3(Bn), dim3(QG * Hn), 0, stream,
                     ws, h0, omega, phase_b, beta, out);
}